// Round 2
// baseline (5301.788 us; speedup 1.0000x reference)
//
#include <hip/hip_runtime.h>
#include <hip/hip_bf16.h>
#include <math.h>

typedef __hip_bfloat16 bf16;

#define B_ 4
#define N_ 1024
#define DIM_ 256
#define HEADS_ 4
#define DH_ 64
#define MLP_ 1024
#define DEPTH_ 4

__device__ __forceinline__ float bf2f(bf16 v){ return __bfloat162float(v); }
__device__ __forceinline__ bf16 f2bf(float v){ return __float2bfloat16(v); }
__device__ __forceinline__ float to_f(float v){ return v; }
__device__ __forceinline__ float to_f(bf16 v){ return __bfloat162float(v); }

__device__ __forceinline__ float gelu_exact(float v){
  return 0.5f*v*(1.0f + erff(v*0.70710678118654752440f));
}

// ---------------- copy ----------------
__global__ void copy_f32(const float* __restrict__ in, float* __restrict__ out, int n){
  int i = blockIdx.x*blockDim.x + threadIdx.x;
  if (i < n) out[i] = in[i];
}

// ---------------- G = softmax(mean_h(bias0) * mean_h(bias1), axis=j) ----------------
// one block per (b,i) row; 256 threads, 4 j's each
__global__ void compute_G(const float* __restrict__ bias, float* __restrict__ G){
  int blk = blockIdx.x;           // b*N + i
  int i = blk & (N_-1);
  int b = blk >> 10;
  int t = threadIdx.x;
  __shared__ float sc[N_];
  __shared__ float red[256];
  long long base0 = ((long long)(b*HEADS_)*N_ + i)*(long long)N_;   // c=0,h=0
  const long long hs = (long long)N_*N_;
  const long long cs = (long long)B_*HEADS_*N_*N_;                  // bias[1] offset
  float lmax = -1e30f;
  for (int jj=0;jj<4;jj++){
    int j = t + jj*256;
    float a = 0.f, s = 0.f;
    #pragma unroll
    for (int h=0;h<HEADS_;h++){
      a += bias[base0 + h*hs + j];
      s += bias[cs + base0 + h*hs + j];
    }
    float v = (a*0.25f)*(s*0.25f);
    sc[j] = v;
    lmax = fmaxf(lmax, v);
  }
  red[t]=lmax; __syncthreads();
  for (int s=128;s>0;s>>=1){ if(t<s) red[t]=fmaxf(red[t],red[t+s]); __syncthreads(); }
  float m = red[0]; __syncthreads();
  float lsum = 0.f;
  for (int jj=0;jj<4;jj++){
    int j = t + jj*256;
    float e = expf(sc[j]-m);
    sc[j]=e; lsum+=e;
  }
  red[t]=lsum; __syncthreads();
  for (int s=128;s>0;s>>=1){ if(t<s) red[t]+=red[t+s]; __syncthreads(); }
  float inv = 1.0f/red[0];
  float* Grow = G + ((long long)b*N_ + i)*(long long)N_;
  for (int jj=0;jj<4;jj++){ int j=t+jj*256; Grow[j]=sc[j]*inv; }
}

// ---------------- LayerNorm over last dim (256), optional relu ----------------
__global__ void ln_kernel(const float* __restrict__ X, float* __restrict__ Y,
                          const float* __restrict__ g, const float* __restrict__ bvec, int relu){
  int row = blockIdx.x, t = threadIdx.x;
  __shared__ float red[256];
  float v = X[(long long)row*DIM_ + t];
  red[t]=v; __syncthreads();
  for (int s=128;s>0;s>>=1){ if(t<s) red[t]+=red[t+s]; __syncthreads(); }
  float mu = red[0]*(1.0f/DIM_); __syncthreads();
  float d = v - mu;
  red[t]=d*d; __syncthreads();
  for (int s=128;s>0;s>>=1){ if(t<s) red[t]+=red[t+s]; __syncthreads(); }
  float var = red[0]*(1.0f/DIM_);
  float y = d*rsqrtf(var+1e-5f)*g[t] + bvec[t];
  if (relu) y = fmaxf(y, 0.0f);
  Y[(long long)row*DIM_ + t] = y;
}

// ---------------- generic tiled GEMM: C = [res +] act(A*B + bias) ----------------
// A fp32 [M,K] lda, B fp32 [K,N] ldb, C fp32 [M,N] ldc. 32x32 tiles, 2x2/thread.
__global__ void gemm_f32(const float* __restrict__ A, const float* __restrict__ Bm, float* C,
    int M, int N, int K, int lda, int ldb, int ldc,
    long long sA, long long sB, long long sC,
    const float* __restrict__ bias, const float* res, int act){
  int zb = blockIdx.z;
  A  += (long long)zb*sA;
  Bm += (long long)zb*sB;
  C  += (long long)zb*sC;
  const float* resp = res ? res + (long long)zb*sC : nullptr;
  __shared__ float As[32][33], Bs[32][33];
  int tx = threadIdx.x, ty = threadIdx.y;
  int t = ty*16 + tx;
  int m0 = blockIdx.y*32, n0 = blockIdx.x*32;
  float a00=0.f,a01=0.f,a10=0.f,a11=0.f;
  for (int k0=0;k0<K;k0+=32){
    #pragma unroll
    for (int q=0;q<4;q++){
      int idx = q*256 + t; int r = idx>>5, c = idx&31;
      As[r][c] = A[(long long)(m0+r)*lda + (k0+c)];
      Bs[r][c] = Bm[(long long)(k0+r)*ldb + (n0+c)];
    }
    __syncthreads();
    #pragma unroll
    for (int kk=0;kk<32;kk++){
      float av0 = As[ty*2][kk], av1 = As[ty*2+1][kk];
      float bv0 = Bs[kk][tx*2], bv1 = Bs[kk][tx*2+1];
      a00 = fmaf(av0,bv0,a00); a01 = fmaf(av0,bv1,a01);
      a10 = fmaf(av1,bv0,a10); a11 = fmaf(av1,bv1,a11);
    }
    __syncthreads();
  }
  int r0 = m0 + ty*2, c0 = n0 + tx*2;
  float bb0 = bias ? bias[c0]   : 0.f;
  float bb1 = bias ? bias[c0+1] : 0.f;
  float v00 = a00+bb0, v01 = a01+bb1, v10 = a10+bb0, v11 = a11+bb1;
  if (act==1){ v00=gelu_exact(v00); v01=gelu_exact(v01); v10=gelu_exact(v10); v11=gelu_exact(v11); }
  if (resp){
    v00 += resp[(long long)r0*ldc + c0];     v01 += resp[(long long)r0*ldc + c0+1];
    v10 += resp[(long long)(r0+1)*ldc + c0]; v11 += resp[(long long)(r0+1)*ldc + c0+1];
  }
  C[(long long)r0*ldc + c0]       = v00; C[(long long)r0*ldc + c0+1]     = v01;
  C[(long long)(r0+1)*ldc + c0]   = v10; C[(long long)(r0+1)*ldc + c0+1] = v11;
}

// ---------------- attention scores + softmax ----------------
// one block per (b,h,i); q fp32 [B*N, DIM] (head h cols h*64..), k = kv[:, 0:256]
// P bf16 [B*H, N, N]
__global__ void attn_scores(const float* __restrict__ q, const float* __restrict__ kv,
                            const float* __restrict__ bias, bf16* __restrict__ P){
  int blk = blockIdx.x;            // ((b*H+h)*N + i)
  int i  = blk & (N_-1);
  int bh = blk >> 10;
  int h  = bh & (HEADS_-1);
  int b  = bh >> 2;
  int t = threadIdx.x;
  __shared__ float qs[DH_];
  __shared__ float sc[N_];
  __shared__ float red[256];
  if (t < DH_) qs[t] = q[((long long)(b*N_+i))*DIM_ + h*DH_ + t];
  __syncthreads();
  long long base0 = (((long long)(b*HEADS_) + h)*N_ + i)*(long long)N_;
  const long long cs = (long long)B_*HEADS_*N_*N_;
  float lmax = -1e30f;
  for (int jj=0;jj<4;jj++){
    int j = t + jj*256;
    const float* kr = kv + ((long long)(b*N_+j))*512 + h*DH_;
    float dot = 0.f;
    #pragma unroll
    for (int d=0; d<DH_; d++) dot = fmaf(qs[d], kr[d], dot);
    float s = dot*0.0625f + bias[base0 + j] + bias[cs + base0 + j];
    sc[j] = s;
    lmax = fmaxf(lmax, s);
  }
  red[t]=lmax; __syncthreads();
  for (int s=128;s>0;s>>=1){ if(t<s) red[t]=fmaxf(red[t],red[t+s]); __syncthreads(); }
  float m = red[0]; __syncthreads();
  float lsum = 0.f;
  for (int jj=0;jj<4;jj++){
    int j = t + jj*256;
    float e = expf(sc[j]-m);
    sc[j]=e; lsum+=e;
  }
  red[t]=lsum; __syncthreads();
  for (int s=128;s>0;s>>=1){ if(t<s) red[t]+=red[t+s]; __syncthreads(); }
  float inv = 1.0f/red[0];
  bf16* Prow = P + ((long long)bh*N_ + i)*(long long)N_;
  for (int jj=0;jj<4;jj++){ int j=t+jj*256; Prow[j] = f2bf(sc[j]*inv); }
}

// ---------------- out = P @ V ----------------
// per (b,h): [1024,1024] @ [1024,64]; V = kv[:, 256 + h*64 ..]; out into [B*N, DIM] at col h*64
__global__ void pv_kernel(const bf16* __restrict__ P, const float* __restrict__ kv, float* __restrict__ out){
  int z = blockIdx.z; int b = z >> 2, h = z & 3;
  const bf16* A = P + (long long)z*N_*N_;
  __shared__ float As[32][33], Bs[32][33];
  int tx=threadIdx.x, ty=threadIdx.y, t=ty*16+tx;
  int m0 = blockIdx.y*32, n0 = blockIdx.x*32;
  float a00=0.f,a01=0.f,a10=0.f,a11=0.f;
  for (int k0=0;k0<N_;k0+=32){
    #pragma unroll
    for (int qq=0;qq<4;qq++){
      int idx=qq*256+t; int r=idx>>5, c=idx&31;
      As[r][c] = bf2f(A[(long long)(m0+r)*N_ + k0 + c]);
      Bs[r][c] = kv[((long long)(b*N_ + k0 + r))*512 + 256 + h*DH_ + n0 + c];
    }
    __syncthreads();
    #pragma unroll
    for (int kk=0;kk<32;kk++){
      float av0=As[ty*2][kk], av1=As[ty*2+1][kk];
      float bv0=Bs[kk][tx*2], bv1=Bs[kk][tx*2+1];
      a00=fmaf(av0,bv0,a00); a01=fmaf(av0,bv1,a01);
      a10=fmaf(av1,bv0,a10); a11=fmaf(av1,bv1,a11);
    }
    __syncthreads();
  }
  int r0=m0+ty*2, c0=n0+tx*2;
  float* o = out + ((long long)(b*N_ + r0))*DIM_ + h*DH_ + c0;
  o[0]=a00; o[1]=a01; o[DIM_]=a10; o[DIM_+1]=a11;
}

// ---------------- host launch ----------------
extern "C" void kernel_launch(void* const* d_in, const int* in_sizes, int n_in,
                              void* d_out, int out_size, void* d_ws, size_t ws_size,
                              hipStream_t stream){
  const float* x_in   = (const float*)d_in[0];
  const float* abias  = (const float*)d_in[1];
  const float* ln1_g  = (const float*)d_in[2];
  const float* ln1_b  = (const float*)d_in[3];
  const float* Wkv    = (const float*)d_in[4];
  const float* Wq     = (const float*)d_in[5];
  const float* Wo     = (const float*)d_in[6];
  const float* bo     = (const float*)d_in[7];
  const float* ln2_g  = (const float*)d_in[8];
  const float* ln2_b  = (const float*)d_in[9];
  const float* W1     = (const float*)d_in[10];
  const float* b1     = (const float*)d_in[11];
  const float* W2     = (const float*)d_in[12];
  const float* b2     = (const float*)d_in[13];
  const float* Wg     = (const float*)d_in[14];
  const float* lng_g  = (const float*)d_in[15];
  const float* lng_b  = (const float*)d_in[16];

  char* ws = (char*)d_ws;
  // workspace layout (76 MB total)
  float* xf   = (float*)(ws + (0ll<<20));    // 4 MB  fp32 residual stream
  float* G    = (float*)(ws + (4ll<<20));    // 16 MB fp32 [B,N,N]
  float* tmp1 = (float*)(ws + (20ll<<20));   // 4 MB  (aliased with q)
  float* tmp2 = (float*)(ws + (24ll<<20));   // 4 MB  (aliased with attn_out)
  float* x_ma = (float*)(ws + (28ll<<20));   // 4 MB
  float* xn   = (float*)(ws + (32ll<<20));   // 4 MB (reused for xn2)
  float* kv   = (float*)(ws + (36ll<<20));   // 8 MB  [B*N, 512] (k | v)
  bf16*  P    = (bf16*) (ws + (44ll<<20));   // 32 MB [B*H,N,N] bf16
  float* h1   = (float*)(ws + (44ll<<20));   // 16 MB, aliased with P (disjoint lifetime)
  float* q    = tmp1;
  float* ao   = tmp2;

  dim3 b256(256);
  dim3 blk(16,16);
  int total = B_*N_*DIM_;

  copy_f32<<<dim3((total+255)/256), b256, 0, stream>>>(x_in, xf, total);
  compute_G<<<dim3(B_*N_), b256, 0, stream>>>(abias, G);

  for (int l=0; l<DEPTH_; l++){
    // tmp1 = G @ x   (batched over B: [1024,1024]@[1024,256])
    gemm_f32<<<dim3(DIM_/32, N_/32, B_), blk, 0, stream>>>(
        G, xf, tmp1, N_, DIM_, N_, N_, DIM_, DIM_,
        (long long)N_*N_, (long long)N_*DIM_, (long long)N_*DIM_,
        nullptr, nullptr, 0);
    // tmp2 = tmp1 @ Wg
    gemm_f32<<<dim3(DIM_/32, (B_*N_)/32, 1), blk, 0, stream>>>(
        tmp1, Wg, tmp2, B_*N_, DIM_, DIM_, DIM_, DIM_, DIM_,
        0,0,0, nullptr, nullptr, 0);
    // x_ma = relu(LN(tmp2))
    ln_kernel<<<dim3(B_*N_), b256, 0, stream>>>(tmp2, x_ma, lng_g, lng_b, 1);
    // xn = LN(x)
    ln_kernel<<<dim3(B_*N_), b256, 0, stream>>>(xf, xn, ln1_g + l*DIM_, ln1_b + l*DIM_, 0);
    // kv = xn @ Wkv[l]  ([4096,256]@[256,512])
    gemm_f32<<<dim3(512/32, (B_*N_)/32, 1), blk, 0, stream>>>(
        xn, Wkv + (long long)l*DIM_*2*DIM_, kv, B_*N_, 2*DIM_, DIM_, DIM_, 2*DIM_, 2*DIM_,
        0,0,0, nullptr, nullptr, 0);
    // q = x_ma @ Wq[l]
    gemm_f32<<<dim3(DIM_/32, (B_*N_)/32, 1), blk, 0, stream>>>(
        x_ma, Wq + (long long)l*DIM_*DIM_, q, B_*N_, DIM_, DIM_, DIM_, DIM_, DIM_,
        0,0,0, nullptr, nullptr, 0);
    // P = softmax(q k^T * scale + bias0 + bias1)
    attn_scores<<<dim3(B_*HEADS_*N_), b256, 0, stream>>>(q, kv, abias, P);
    // ao = P @ V
    pv_kernel<<<dim3(DH_/32, N_/32, B_*HEADS_), blk, 0, stream>>>(P, kv, ao);
    // x = x + ao @ Wo[l] + bo[l]
    gemm_f32<<<dim3(DIM_/32, (B_*N_)/32, 1), blk, 0, stream>>>(
        ao, Wo + (long long)l*DIM_*DIM_, xf, B_*N_, DIM_, DIM_, DIM_, DIM_, DIM_,
        0,0,0, bo + l*DIM_, xf, 0);
    // xn2 = LN(x)
    ln_kernel<<<dim3(B_*N_), b256, 0, stream>>>(xf, xn, ln2_g + l*DIM_, ln2_b + l*DIM_, 0);
    // h1 = gelu(xn2 @ W1[l] + b1[l])
    gemm_f32<<<dim3(MLP_/32, (B_*N_)/32, 1), blk, 0, stream>>>(
        xn, W1 + (long long)l*DIM_*MLP_, h1, B_*N_, MLP_, DIM_, DIM_, MLP_, MLP_,
        0,0,0, b1 + l*MLP_, nullptr, 1);
    // x = x + h1 @ W2[l] + b2[l]   (last layer writes straight to d_out)
    float* Cdst = (l == DEPTH_-1) ? (float*)d_out : xf;
    gemm_f32<<<dim3(DIM_/32, (B_*N_)/32, 1), blk, 0, stream>>>(
        h1, W2 + (long long)l*MLP_*DIM_, Cdst, B_*N_, DIM_, MLP_, MLP_, DIM_, DIM_,
        0,0,0, b2 + l*DIM_, xf, 0);
  }
}

// Round 3
// 2226.993 us; speedup vs baseline: 2.3807x; 2.3807x over previous
//
#include <hip/hip_runtime.h>
#include <hip/hip_bf16.h>
#include <math.h>

typedef __hip_bfloat16 bf16;

#define B_ 4
#define N_ 1024
#define DIM_ 256
#define HEADS_ 4
#define DH_ 64
#define MLP_ 1024
#define DEPTH_ 4

__device__ __forceinline__ float gelu_exact(float v){
  return 0.5f*v*(1.0f + erff(v*0.70710678118654752440f));
}

// ---------------- copy ----------------
__global__ void copy_f32(const float* __restrict__ in, float* __restrict__ out, int n){
  int i = blockIdx.x*blockDim.x + threadIdx.x;
  if (i < n) out[i] = in[i];
}

// ---------------- G = softmax(mean_h(bias0) * mean_h(bias1), axis=j) ----------------
__global__ void compute_G(const float* __restrict__ bias, float* __restrict__ G){
  int blk = blockIdx.x;           // b*N + i
  int i = blk & (N_-1);
  int b = blk >> 10;
  int t = threadIdx.x;
  __shared__ float sc[N_];
  __shared__ float red[256];
  long long base0 = ((long long)(b*HEADS_)*N_ + i)*(long long)N_;
  const long long hs = (long long)N_*N_;
  const long long cs = (long long)B_*HEADS_*N_*N_;
  float lmax = -1e30f;
  for (int jj=0;jj<4;jj++){
    int j = t + jj*256;
    float a = 0.f, s = 0.f;
    #pragma unroll
    for (int h=0;h<HEADS_;h++){
      a += bias[base0 + h*hs + j];
      s += bias[cs + base0 + h*hs + j];
    }
    float v = (a*0.25f)*(s*0.25f);
    sc[j] = v;
    lmax = fmaxf(lmax, v);
  }
  red[t]=lmax; __syncthreads();
  for (int s=128;s>0;s>>=1){ if(t<s) red[t]=fmaxf(red[t],red[t+s]); __syncthreads(); }
  float m = red[0]; __syncthreads();
  float lsum = 0.f;
  for (int jj=0;jj<4;jj++){
    int j = t + jj*256;
    float e = expf(sc[j]-m);
    sc[j]=e; lsum+=e;
  }
  red[t]=lsum; __syncthreads();
  for (int s=128;s>0;s>>=1){ if(t<s) red[t]+=red[t+s]; __syncthreads(); }
  float inv = 1.0f/red[0];
  float* Grow = G + ((long long)b*N_ + i)*(long long)N_;
  for (int jj=0;jj<4;jj++){ int j=t+jj*256; Grow[j]=sc[j]*inv; }
}

// ---------------- LayerNorm over last dim (256), optional relu ----------------
__global__ void ln_kernel(const float* __restrict__ X, float* __restrict__ Y,
                          const float* __restrict__ g, const float* __restrict__ bvec, int relu){
  int row = blockIdx.x, t = threadIdx.x;
  __shared__ float red[256];
  float v = X[(long long)row*DIM_ + t];
  red[t]=v; __syncthreads();
  for (int s=128;s>0;s>>=1){ if(t<s) red[t]+=red[t+s]; __syncthreads(); }
  float mu = red[0]*(1.0f/DIM_); __syncthreads();
  float d = v - mu;
  red[t]=d*d; __syncthreads();
  for (int s=128;s>0;s>>=1){ if(t<s) red[t]+=red[t+s]; __syncthreads(); }
  float var = red[0]*(1.0f/DIM_);
  float y = d*rsqrtf(var+1e-5f)*g[t] + bvec[t];
  if (relu) y = fmaxf(y, 0.0f);
  Y[(long long)row*DIM_ + t] = y;
}

// ---------------- generic tiled GEMM: C = [res +] act(A*B + bias) ----------------
__global__ void gemm_f32(const float* __restrict__ A, const float* __restrict__ Bm, float* C,
    int M, int N, int K, int lda, int ldb, int ldc,
    long long sA, long long sB, long long sC,
    const float* __restrict__ bias, const float* res, int act){
  int zb = blockIdx.z;
  A  += (long long)zb*sA;
  Bm += (long long)zb*sB;
  C  += (long long)zb*sC;
  const float* resp = res ? res + (long long)zb*sC : nullptr;
  __shared__ float As[32][33], Bs[32][33];
  int tx = threadIdx.x, ty = threadIdx.y;
  int t = ty*16 + tx;
  int m0 = blockIdx.y*32, n0 = blockIdx.x*32;
  float a00=0.f,a01=0.f,a10=0.f,a11=0.f;
  for (int k0=0;k0<K;k0+=32){
    #pragma unroll
    for (int q=0;q<4;q++){
      int idx = q*256 + t; int r = idx>>5, c = idx&31;
      As[r][c] = A[(long long)(m0+r)*lda + (k0+c)];
      Bs[r][c] = Bm[(long long)(k0+r)*ldb + (n0+c)];
    }
    __syncthreads();
    #pragma unroll
    for (int kk=0;kk<32;kk++){
      float av0 = As[ty*2][kk], av1 = As[ty*2+1][kk];
      float bv0 = Bs[kk][tx*2], bv1 = Bs[kk][tx*2+1];
      a00 = fmaf(av0,bv0,a00); a01 = fmaf(av0,bv1,a01);
      a10 = fmaf(av1,bv0,a10); a11 = fmaf(av1,bv1,a11);
    }
    __syncthreads();
  }
  int r0 = m0 + ty*2, c0 = n0 + tx*2;
  float bb0 = bias ? bias[c0]   : 0.f;
  float bb1 = bias ? bias[c0+1] : 0.f;
  float v00 = a00+bb0, v01 = a01+bb1, v10 = a10+bb0, v11 = a11+bb1;
  if (act==1){ v00=gelu_exact(v00); v01=gelu_exact(v01); v10=gelu_exact(v10); v11=gelu_exact(v11); }
  if (resp){
    v00 += resp[(long long)r0*ldc + c0];     v01 += resp[(long long)r0*ldc + c0+1];
    v10 += resp[(long long)(r0+1)*ldc + c0]; v11 += resp[(long long)(r0+1)*ldc + c0+1];
  }
  C[(long long)r0*ldc + c0]       = v00; C[(long long)r0*ldc + c0+1]     = v01;
  C[(long long)(r0+1)*ldc + c0]   = v10; C[(long long)(r0+1)*ldc + c0+1] = v11;
}

// ---------------- score GEMM: S[bh][i][j] = (Q K^T)*scale + bias0 + bias1 ----------------
// Q = q[B*N,256] cols h*64.. ; K = kv[B*N,512] cols h*64.. ; K staged transposed into LDS.
__global__ void score_gemm(const float* __restrict__ q, const float* __restrict__ kv,
                           const float* __restrict__ bias, float* __restrict__ S){
  int bh = blockIdx.z; int h = bh & 3, b = bh >> 2;
  __shared__ float As[32][33];   // [m][k]
  __shared__ float Bs[32][33];   // [k][n]  (written transposed)
  int tx = threadIdx.x, ty = threadIdx.y;
  int t = ty*16 + tx;
  int m0 = blockIdx.y*32, n0 = blockIdx.x*32;
  int c = t & 31, r8 = t >> 5;   // staging: c = inner col (coalesced), r8 = row group
  float a00=0.f,a01=0.f,a10=0.f,a11=0.f;
  #pragma unroll
  for (int k0=0;k0<DH_;k0+=32){
    #pragma unroll
    for (int s=0;s<4;s++){
      int r = r8 + 8*s;
      // A tile: rows = q rows (coalesced over k cols)
      As[r][c] = q[(long long)(b*N_ + m0 + r)*DIM_ + h*DH_ + k0 + c];
      // K tile: read row n0+r (coalesced over k cols), write transposed -> Bs[k][n]
      Bs[c][r] = kv[(long long)(b*N_ + n0 + r)*512 + h*DH_ + k0 + c];
    }
    __syncthreads();
    #pragma unroll
    for (int kk=0;kk<32;kk++){
      float av0 = As[ty*2][kk], av1 = As[ty*2+1][kk];
      float bv0 = Bs[kk][tx*2], bv1 = Bs[kk][tx*2+1];
      a00 = fmaf(av0,bv0,a00); a01 = fmaf(av0,bv1,a01);
      a10 = fmaf(av1,bv0,a10); a11 = fmaf(av1,bv1,a11);
    }
    __syncthreads();
  }
  int r0 = m0 + ty*2, c0 = n0 + tx*2;
  const long long cs = (long long)B_*HEADS_*N_*N_;
  long long i0 = ((long long)bh*N_ + r0)*N_ + c0;   // same layout for bias0 and S
  long long i1 = i0 + N_;                            // next row
  const float scale = 0.0625f;  // DIM^-0.5 = 1/16
  S[i0]   = a00*scale + bias[i0]   + bias[cs+i0];
  S[i0+1] = a01*scale + bias[i0+1] + bias[cs+i0+1];
  S[i1]   = a10*scale + bias[i1]   + bias[cs+i1];
  S[i1+1] = a11*scale + bias[i1+1] + bias[cs+i1+1];
}

// ---------------- in-place row softmax over last dim (1024) ----------------
__global__ void softmax_rows(float* __restrict__ S){
  long long row = blockIdx.x;
  float* Sr = S + row*(long long)N_;
  int t = threadIdx.x;
  __shared__ float red[256];
  float4 v = ((float4*)Sr)[t];
  float lmax = fmaxf(fmaxf(v.x,v.y), fmaxf(v.z,v.w));
  red[t]=lmax; __syncthreads();
  for (int s=128;s>0;s>>=1){ if(t<s) red[t]=fmaxf(red[t],red[t+s]); __syncthreads(); }
  float m = red[0]; __syncthreads();
  v.x = expf(v.x-m); v.y = expf(v.y-m); v.z = expf(v.z-m); v.w = expf(v.w-m);
  float lsum = v.x+v.y+v.z+v.w;
  red[t]=lsum; __syncthreads();
  for (int s=128;s>0;s>>=1){ if(t<s) red[t]+=red[t+s]; __syncthreads(); }
  float inv = 1.0f/red[0];
  v.x*=inv; v.y*=inv; v.z*=inv; v.w*=inv;
  ((float4*)Sr)[t] = v;
}

// ---------------- out = P @ V ----------------
// per (b,h): [1024,1024] @ [1024,64]; P fp32; V = kv[:, 256 + h*64 ..]
__global__ void pv_kernel(const float* __restrict__ P, const float* __restrict__ kv, float* __restrict__ out){
  int z = blockIdx.z; int b = z >> 2, h = z & 3;
  const float* A = P + (long long)z*N_*N_;
  __shared__ float As[32][33], Bs[32][33];
  int tx=threadIdx.x, ty=threadIdx.y, t=ty*16+tx;
  int m0 = blockIdx.y*32, n0 = blockIdx.x*32;
  float a00=0.f,a01=0.f,a10=0.f,a11=0.f;
  for (int k0=0;k0<N_;k0+=32){
    #pragma unroll
    for (int qq=0;qq<4;qq++){
      int idx=qq*256+t; int r=idx>>5, c=idx&31;
      As[r][c] = A[(long long)(m0+r)*N_ + k0 + c];
      Bs[r][c] = kv[((long long)(b*N_ + k0 + r))*512 + 256 + h*DH_ + n0 + c];
    }
    __syncthreads();
    #pragma unroll
    for (int kk=0;kk<32;kk++){
      float av0=As[ty*2][kk], av1=As[ty*2+1][kk];
      float bv0=Bs[kk][tx*2], bv1=Bs[kk][tx*2+1];
      a00=fmaf(av0,bv0,a00); a01=fmaf(av0,bv1,a01);
      a10=fmaf(av1,bv0,a10); a11=fmaf(av1,bv1,a11);
    }
    __syncthreads();
  }
  int r0=m0+ty*2, c0=n0+tx*2;
  float* o = out + ((long long)(b*N_ + r0))*DIM_ + h*DH_ + c0;
  o[0]=a00; o[1]=a01; o[DIM_]=a10; o[DIM_+1]=a11;
}

// ---------------- host launch ----------------
extern "C" void kernel_launch(void* const* d_in, const int* in_sizes, int n_in,
                              void* d_out, int out_size, void* d_ws, size_t ws_size,
                              hipStream_t stream){
  const float* x_in   = (const float*)d_in[0];
  const float* abias  = (const float*)d_in[1];
  const float* ln1_g  = (const float*)d_in[2];
  const float* ln1_b  = (const float*)d_in[3];
  const float* Wkv    = (const float*)d_in[4];
  const float* Wq     = (const float*)d_in[5];
  const float* Wo     = (const float*)d_in[6];
  const float* bo     = (const float*)d_in[7];
  const float* ln2_g  = (const float*)d_in[8];
  const float* ln2_b  = (const float*)d_in[9];
  const float* W1     = (const float*)d_in[10];
  const float* b1     = (const float*)d_in[11];
  const float* W2     = (const float*)d_in[12];
  const float* b2     = (const float*)d_in[13];
  const float* Wg     = (const float*)d_in[14];
  const float* lng_g  = (const float*)d_in[15];
  const float* lng_b  = (const float*)d_in[16];

  char* ws = (char*)d_ws;
  // workspace layout (108 MB total)
  float* xf   = (float*)(ws + (0ll<<20));    // 4 MB  fp32 residual stream
  float* G    = (float*)(ws + (4ll<<20));    // 16 MB fp32 [B,N,N]
  float* tmp1 = (float*)(ws + (20ll<<20));   // 4 MB  (aliased with q)
  float* tmp2 = (float*)(ws + (24ll<<20));   // 4 MB  (aliased with attn_out)
  float* x_ma = (float*)(ws + (28ll<<20));   // 4 MB
  float* xn   = (float*)(ws + (32ll<<20));   // 4 MB (reused for xn2)
  float* kv   = (float*)(ws + (36ll<<20));   // 8 MB  [B*N, 512] (k | v)
  float* S    = (float*)(ws + (44ll<<20));   // 64 MB fp32 [B*H,N,N] scores->probs
  float* h1   = (float*)(ws + (44ll<<20));   // 16 MB, aliased with S (disjoint lifetime)
  float* q    = tmp1;
  float* ao   = tmp2;

  dim3 b256(256);
  dim3 blk(16,16);
  int total = B_*N_*DIM_;

  copy_f32<<<dim3((total+255)/256), b256, 0, stream>>>(x_in, xf, total);
  compute_G<<<dim3(B_*N_), b256, 0, stream>>>(abias, G);

  for (int l=0; l<DEPTH_; l++){
    // tmp1 = G @ x   (batched over B: [1024,1024]@[1024,256])
    gemm_f32<<<dim3(DIM_/32, N_/32, B_), blk, 0, stream>>>(
        G, xf, tmp1, N_, DIM_, N_, N_, DIM_, DIM_,
        (long long)N_*N_, (long long)N_*DIM_, (long long)N_*DIM_,
        nullptr, nullptr, 0);
    // tmp2 = tmp1 @ Wg
    gemm_f32<<<dim3(DIM_/32, (B_*N_)/32, 1), blk, 0, stream>>>(
        tmp1, Wg, tmp2, B_*N_, DIM_, DIM_, DIM_, DIM_, DIM_,
        0,0,0, nullptr, nullptr, 0);
    // x_ma = relu(LN(tmp2))
    ln_kernel<<<dim3(B_*N_), b256, 0, stream>>>(tmp2, x_ma, lng_g, lng_b, 1);
    // xn = LN(x)
    ln_kernel<<<dim3(B_*N_), b256, 0, stream>>>(xf, xn, ln1_g + l*DIM_, ln1_b + l*DIM_, 0);
    // kv = xn @ Wkv[l]  ([4096,256]@[256,512])
    gemm_f32<<<dim3(512/32, (B_*N_)/32, 1), blk, 0, stream>>>(
        xn, Wkv + (long long)l*DIM_*2*DIM_, kv, B_*N_, 2*DIM_, DIM_, DIM_, 2*DIM_, 2*DIM_,
        0,0,0, nullptr, nullptr, 0);
    // q = x_ma @ Wq[l]
    gemm_f32<<<dim3(DIM_/32, (B_*N_)/32, 1), blk, 0, stream>>>(
        x_ma, Wq + (long long)l*DIM_*DIM_, q, B_*N_, DIM_, DIM_, DIM_, DIM_, DIM_,
        0,0,0, nullptr, nullptr, 0);
    // S = q k^T * scale + bias0 + bias1
    score_gemm<<<dim3(N_/32, N_/32, B_*HEADS_), blk, 0, stream>>>(q, kv, abias, S);
    // P = softmax(S) in-place
    softmax_rows<<<dim3(B_*HEADS_*N_), b256, 0, stream>>>(S);
    // ao = P @ V
    pv_kernel<<<dim3(DH_/32, N_/32, B_*HEADS_), blk, 0, stream>>>(S, kv, ao);
    // x = x + ao @ Wo[l] + bo[l]
    gemm_f32<<<dim3(DIM_/32, (B_*N_)/32, 1), blk, 0, stream>>>(
        ao, Wo + (long long)l*DIM_*DIM_, xf, B_*N_, DIM_, DIM_, DIM_, DIM_, DIM_,
        0,0,0, bo + l*DIM_, xf, 0);
    // xn2 = LN(x)
    ln_kernel<<<dim3(B_*N_), b256, 0, stream>>>(xf, xn, ln2_g + l*DIM_, ln2_b + l*DIM_, 0);
    // h1 = gelu(xn2 @ W1[l] + b1[l])
    gemm_f32<<<dim3(MLP_/32, (B_*N_)/32, 1), blk, 0, stream>>>(
        xn, W1 + (long long)l*DIM_*MLP_, h1, B_*N_, MLP_, DIM_, DIM_, MLP_, MLP_,
        0,0,0, b1 + l*MLP_, nullptr, 1);
    // x = x + h1 @ W2[l] + b2[l]   (last layer writes straight to d_out)
    float* Cdst = (l == DEPTH_-1) ? (float*)d_out : xf;
    gemm_f32<<<dim3(DIM_/32, (B_*N_)/32, 1), blk, 0, stream>>>(
        h1, W2 + (long long)l*MLP_*DIM_, Cdst, B_*N_, DIM_, MLP_, MLP_, DIM_, DIM_,
        0,0,0, b2 + l*DIM_, xf, 0);
  }
}

// Round 4
// 853.969 us; speedup vs baseline: 6.2084x; 2.6078x over previous
//
#include <hip/hip_runtime.h>
#include <hip/hip_bf16.h>
#include <math.h>

typedef unsigned short u16;
typedef __bf16 bf16x8 __attribute__((ext_vector_type(8)));
typedef float f32x4 __attribute__((ext_vector_type(4)));

#define B_ 4
#define N_ 1024
#define DIM_ 256
#define HEADS_ 4
#define DH_ 64
#define MLP_ 1024
#define DEPTH_ 4

__device__ __forceinline__ float r2f(u16 r){ return __uint_as_float(((unsigned)r)<<16); }
__device__ __forceinline__ u16 f2r(float f){ __hip_bfloat16 h = __float2bfloat16(f); return *(u16*)&h; }
__device__ __forceinline__ float ldv(const float* p){ return *p; }
__device__ __forceinline__ float ldv(const u16* p){ return r2f(*p); }
__device__ __forceinline__ void stv(float* p, float v){ *p = v; }
__device__ __forceinline__ void stv(u16* p, float v){ *p = f2r(v); }

__device__ __forceinline__ float gelu_exact(float v){
  return 0.5f*v*(1.0f + erff(v*0.70710678118654752440f));
}

// ---------------- copy ----------------
__global__ void copy_f32(const float* __restrict__ in, float* __restrict__ out, int n){
  int i = blockIdx.x*blockDim.x + threadIdx.x;
  if (i < n) out[i] = in[i];
}

// ---------------- bsum = bf16(bias0 + bias1) ----------------
__global__ void bias_sum_k(const float* __restrict__ b, u16* __restrict__ o){
  int i = blockIdx.x*blockDim.x + threadIdx.x;   // one float4 per thread
  const long long cs = (long long)B_*HEADS_*N_*N_;
  float4 a = ((const float4*)b)[i];
  float4 s = ((const float4*)(b + cs))[i];
  ushort4 r;
  r.x = f2r(a.x + s.x); r.y = f2r(a.y + s.y);
  r.z = f2r(a.z + s.z); r.w = f2r(a.w + s.w);
  ((ushort4*)o)[i] = r;
}

// ---------------- G = softmax(mean_h(b0) * mean_h(b1)) -> bf16 ----------------
__global__ void compute_G(const float* __restrict__ bias, u16* __restrict__ G){
  int blk = blockIdx.x;           // b*N + i
  int i = blk & (N_-1);
  int b = blk >> 10;
  int t = threadIdx.x;
  __shared__ float sc[N_];
  __shared__ float red[256];
  long long base0 = ((long long)(b*HEADS_)*N_ + i)*(long long)N_;
  const long long hs = (long long)N_*N_;
  const long long cs = (long long)B_*HEADS_*N_*N_;
  float lmax = -1e30f;
  for (int jj=0;jj<4;jj++){
    int j = t + jj*256;
    float a = 0.f, s = 0.f;
    #pragma unroll
    for (int h=0;h<HEADS_;h++){
      a += bias[base0 + h*hs + j];
      s += bias[cs + base0 + h*hs + j];
    }
    float v = (a*0.25f)*(s*0.25f);
    sc[j] = v;
    lmax = fmaxf(lmax, v);
  }
  red[t]=lmax; __syncthreads();
  for (int s=128;s>0;s>>=1){ if(t<s) red[t]=fmaxf(red[t],red[t+s]); __syncthreads(); }
  float m = red[0]; __syncthreads();
  float lsum = 0.f;
  for (int jj=0;jj<4;jj++){
    int j = t + jj*256;
    float e = expf(sc[j]-m);
    sc[j]=e; lsum+=e;
  }
  red[t]=lsum; __syncthreads();
  for (int s=128;s>0;s>>=1){ if(t<s) red[t]+=red[t+s]; __syncthreads(); }
  float inv = 1.0f/red[0];
  u16* Grow = G + ((long long)b*N_ + i)*(long long)N_;
  for (int jj=0;jj<4;jj++){ int j=t+jj*256; Grow[j]=f2r(sc[j]*inv); }
}

// ---------------- LayerNorm (dim 256), fp32 math, bf16 out ----------------
template<typename TIN>
__global__ void ln_kernel(const TIN* __restrict__ X, u16* __restrict__ Y,
                          const float* __restrict__ g, const float* __restrict__ bvec, int relu){
  int row = blockIdx.x, t = threadIdx.x;
  __shared__ float red[256];
  float v = ldv(X + (long long)row*DIM_ + t);
  red[t]=v; __syncthreads();
  for (int s=128;s>0;s>>=1){ if(t<s) red[t]+=red[t+s]; __syncthreads(); }
  float mu = red[0]*(1.0f/DIM_); __syncthreads();
  float d = v - mu;
  red[t]=d*d; __syncthreads();
  for (int s=128;s>0;s>>=1){ if(t<s) red[t]+=red[t+s]; __syncthreads(); }
  float var = red[0]*(1.0f/DIM_);
  float y = d*rsqrtf(var+1e-5f)*g[t] + bvec[t];
  if (relu) y = fmaxf(y, 0.0f);
  Y[(long long)row*DIM_ + t] = f2r(y);
}

// ---------------- transpose + cast to bf16: out[c][r] = in[r][c] ----------------
// block (32,8); grid (C/32, R/32, Z); out ld = R
template<typename TIN>
__global__ void tcast(const TIN* __restrict__ in, u16* __restrict__ out,
                      int ldin, int R, long long sIn, long long sOut){
  __shared__ float tile[32][33];
  int z = blockIdx.z;
  const TIN* I = in + (long long)z*sIn;
  u16* O = out + (long long)z*sOut;
  int c0 = blockIdx.x*32, r0 = blockIdx.y*32;
  int tx = threadIdx.x, ty = threadIdx.y;
  #pragma unroll
  for (int i=0;i<4;i++)
    tile[ty*4+i][tx] = ldv(I + (long long)(r0+ty*4+i)*ldin + c0+tx);
  __syncthreads();
  #pragma unroll
  for (int i=0;i<4;i++)
    O[(long long)(c0+ty*4+i)*R + r0+tx] = f2r(tile[tx][ty*4+i]);
}

// ---------------- in-place row softmax over 1024, bf16 ----------------
__global__ void softmax_rows(u16* __restrict__ S){
  long long row = blockIdx.x;
  u16* Sr = S + row*(long long)N_;
  int t = threadIdx.x;
  __shared__ float red[256];
  ushort4 u = ((ushort4*)Sr)[t];
  float x0=r2f(u.x), x1=r2f(u.y), x2=r2f(u.z), x3=r2f(u.w);
  float lmax = fmaxf(fmaxf(x0,x1), fmaxf(x2,x3));
  red[t]=lmax; __syncthreads();
  for (int s=128;s>0;s>>=1){ if(t<s) red[t]=fmaxf(red[t],red[t+s]); __syncthreads(); }
  float m = red[0]; __syncthreads();
  x0=expf(x0-m); x1=expf(x1-m); x2=expf(x2-m); x3=expf(x3-m);
  red[t]=x0+x1+x2+x3; __syncthreads();
  for (int s=128;s>0;s>>=1){ if(t<s) red[t]+=red[t+s]; __syncthreads(); }
  float inv = 1.0f/red[0];
  u.x=f2r(x0*inv); u.y=f2r(x1*inv); u.z=f2r(x2*inv); u.w=f2r(x3*inv);
  ((ushort4*)Sr)[t] = u;
}

// ---------------- unified bf16 MFMA GEMM: C = [res +] act(alpha*A@BT^T + colBias + matBias) ----
// A [M,K] bf16 row-major (lda); BT [N,K] bf16 row-major (ldbt); C [M,N] (ldc), OT=float|u16.
// z decomposition: z = (zb<<ZS)|zh; per-operand (zb,zh) strides. matBias/res share C offsets.
template<typename OT, int ACT>
__global__ __launch_bounds__(256) void mfma_bt(
    const u16* __restrict__ A, const u16* __restrict__ BT, OT* __restrict__ Cbase,
    int K, int lda, int ldbt, int ldc, int ZS,
    long long sAb, long long sAh, long long sBb, long long sBh,
    long long sCb, long long sCh,
    float alpha, const float* __restrict__ colBias,
    const u16* __restrict__ matBias, const float* __restrict__ res)
{
  int z = blockIdx.z, zb = z>>ZS, zh = z & ((1<<ZS)-1);
  A  += zb*sAb + zh*sAh;
  BT += zb*sBb + zh*sBh;
  long long co = zb*sCb + zh*sCh;
  OT* C = Cbase + co;
  const u16* mB = matBias ? matBias + co : nullptr;
  const float* rs = res ? res + co : nullptr;

  __shared__ alignas(16) __bf16 As[64][72];
  __shared__ alignas(16) __bf16 Bs[64][72];
  int tid = threadIdx.x;
  int m0 = blockIdx.y*64, n0 = blockIdx.x*64;
  int w = tid>>6, lane = tid&63;
  int wr = (w>>1)*32, wc = (w&1)*32;
  int lrow = lane&15, qd = lane>>4;
  int sr = tid>>2, sseg = (tid&3)*16;

  f32x4 acc[2][2] = {};
  for (int k0=0; k0<K; k0+=64){
    const u16* Ag = A + (long long)(m0+sr)*lda + k0 + sseg;
    uint4 a0 = *(const uint4*)Ag;
    uint4 a1 = *(const uint4*)(Ag+8);
    const u16* Bg = BT + (long long)(n0+sr)*ldbt + k0 + sseg;
    uint4 b0 = *(const uint4*)Bg;
    uint4 b1 = *(const uint4*)(Bg+8);
    *(uint4*)&As[sr][sseg]   = a0;
    *(uint4*)&As[sr][sseg+8] = a1;
    *(uint4*)&Bs[sr][sseg]   = b0;
    *(uint4*)&Bs[sr][sseg+8] = b1;
    __syncthreads();
    #pragma unroll
    for (int ks=0; ks<2; ks++){
      bf16x8 af0 = *(const bf16x8*)&As[wr + lrow     ][ks*32 + qd*8];
      bf16x8 af1 = *(const bf16x8*)&As[wr + 16 + lrow][ks*32 + qd*8];
      bf16x8 bf0 = *(const bf16x8*)&Bs[wc + lrow     ][ks*32 + qd*8];
      bf16x8 bf1 = *(const bf16x8*)&Bs[wc + 16 + lrow][ks*32 + qd*8];
      acc[0][0] = __builtin_amdgcn_mfma_f32_16x16x32_bf16(af0, bf0, acc[0][0], 0,0,0);
      acc[0][1] = __builtin_amdgcn_mfma_f32_16x16x32_bf16(af0, bf1, acc[0][1], 0,0,0);
      acc[1][0] = __builtin_amdgcn_mfma_f32_16x16x32_bf16(af1, bf0, acc[1][0], 0,0,0);
      acc[1][1] = __builtin_amdgcn_mfma_f32_16x16x32_bf16(af1, bf1, acc[1][1], 0,0,0);
    }
    __syncthreads();
  }
  #pragma unroll
  for (int rt=0;rt<2;rt++){
    #pragma unroll
    for (int ct=0;ct<2;ct++){
      int gcol = n0 + wc + ct*16 + lrow;
      float cb = colBias ? colBias[gcol] : 0.f;
      #pragma unroll
      for (int r=0;r<4;r++){
        int grow = m0 + wr + rt*16 + qd*4 + r;
        float v = acc[rt][ct][r]*alpha + cb;
        if (mB) v += r2f(mB[(long long)grow*ldc + gcol]);
        if (ACT) v = gelu_exact(v);
        if (rs) v += rs[(long long)grow*ldc + gcol];
        stv(C + (long long)grow*ldc + gcol, v);
      }
    }
  }
}

// ---------------- host-side gemm dispatch ----------------
static inline void gemm(hipStream_t st, const u16* A, const u16* BT, void* C, int outBf, int act,
    int M, int N, int K, int lda, int ldbt, int ldc, int Z, int ZS,
    long long sAb, long long sAh, long long sBb, long long sBh, long long sCb, long long sCh,
    float alpha, const float* cb, const u16* mb, const float* res)
{
  dim3 g(N/64, M/64, Z), b(256);
  if (outBf){
    if (act) mfma_bt<u16,1><<<g,b,0,st>>>(A,BT,(u16*)C,K,lda,ldbt,ldc,ZS,sAb,sAh,sBb,sBh,sCb,sCh,alpha,cb,mb,res);
    else     mfma_bt<u16,0><<<g,b,0,st>>>(A,BT,(u16*)C,K,lda,ldbt,ldc,ZS,sAb,sAh,sBb,sBh,sCb,sCh,alpha,cb,mb,res);
  } else {
    if (act) mfma_bt<float,1><<<g,b,0,st>>>(A,BT,(float*)C,K,lda,ldbt,ldc,ZS,sAb,sAh,sBb,sBh,sCb,sCh,alpha,cb,mb,res);
    else     mfma_bt<float,0><<<g,b,0,st>>>(A,BT,(float*)C,K,lda,ldbt,ldc,ZS,sAb,sAh,sBb,sBh,sCb,sCh,alpha,cb,mb,res);
  }
}

// ---------------- host launch ----------------
extern "C" void kernel_launch(void* const* d_in, const int* in_sizes, int n_in,
                              void* d_out, int out_size, void* d_ws, size_t ws_size,
                              hipStream_t stream){
  const float* x_in   = (const float*)d_in[0];
  const float* abias  = (const float*)d_in[1];
  const float* ln1_g  = (const float*)d_in[2];
  const float* ln1_b  = (const float*)d_in[3];
  const float* Wkv    = (const float*)d_in[4];
  const float* Wq     = (const float*)d_in[5];
  const float* Wo     = (const float*)d_in[6];
  const float* bo     = (const float*)d_in[7];
  const float* ln2_g  = (const float*)d_in[8];
  const float* ln2_b  = (const float*)d_in[9];
  const float* W1     = (const float*)d_in[10];
  const float* b1     = (const float*)d_in[11];
  const float* W2     = (const float*)d_in[12];
  const float* b2     = (const float*)d_in[13];
  const float* Wg     = (const float*)d_in[14];
  const float* lng_g  = (const float*)d_in[15];
  const float* lng_b  = (const float*)d_in[16];

  char* ws = (char*)d_ws;
  float* xf   = (float*)(ws);                               // 4 MB fp32 residual
  u16*  Gb    = (u16*)(ws + (4ll<<20));                     // 8 MB  [B,1024,1024]
  u16*  bsum  = (u16*)(ws + (12ll<<20));                    // 32 MB [B*H,1024,1024]
  u16*  S     = (u16*)(ws + (44ll<<20));                    // 32 MB scores->probs
  u16*  kvb   = (u16*)(ws + (76ll<<20));                    // 4 MB  [4096,512]
  u16*  vt    = (u16*)(ws + (80ll<<20));                    // 2 MB  [B,256,1024]
  u16*  xT    = (u16*)(ws + (82ll<<20));                    // 2 MB  [B,256,1024]
  u16*  tmp1b = (u16*)(ws + (84ll<<20));                    // 2 MB (alias qb)
  u16*  tmp2b = (u16*)(ws + (86ll<<20));                    // 2 MB
  u16*  xnb   = (u16*)(ws + (88ll<<20));                    // 2 MB
  u16*  xmab  = (u16*)(ws + (90ll<<20));                    // 2 MB (alias aob)
  u16*  h1b   = (u16*)(ws + (92ll<<20));                    // 8 MB [4096,1024]
  u16*  WkvT  = (u16*)(ws + (100ll<<20));                   // 1 MB [l][512,256]
  u16*  WqT   = (u16*)(ws + (101ll<<20));                   // 0.5 MB
  u16*  WoT   = (u16*)(ws + (101ll<<20) + (512ll<<10));     // 0.5 MB
  u16*  W1T   = (u16*)(ws + (102ll<<20));                   // 2 MB [l][1024,256]
  u16*  W2T   = (u16*)(ws + (104ll<<20));                   // 2 MB [l][256,1024]
  u16*  WgT   = (u16*)(ws + (106ll<<20));                   // 0.125 MB
  u16*  qb    = tmp1b;
  u16*  aob   = xmab;

  dim3 b256(256);
  dim3 tblk(32,8);
  int total = B_*N_*DIM_;

  // ---- one-time preprocessing (every call) ----
  copy_f32<<<dim3((total+255)/256), b256, 0, stream>>>(x_in, xf, total);
  compute_G<<<dim3(B_*N_), b256, 0, stream>>>(abias, Gb);
  bias_sum_k<<<dim3(16384), b256, 0, stream>>>(abias, bsum);
  tcast<float><<<dim3(16,8,DEPTH_),  tblk, 0, stream>>>(Wkv, WkvT, 512, 256, 131072, 131072);
  tcast<float><<<dim3(8,8,DEPTH_),   tblk, 0, stream>>>(Wq,  WqT,  256, 256, 65536, 65536);
  tcast<float><<<dim3(8,8,DEPTH_),   tblk, 0, stream>>>(Wo,  WoT,  256, 256, 65536, 65536);
  tcast<float><<<dim3(32,8,DEPTH_),  tblk, 0, stream>>>(W1,  W1T,  1024, 256, 262144, 262144);
  tcast<float><<<dim3(8,32,DEPTH_),  tblk, 0, stream>>>(W2,  W2T,  256, 1024, 262144, 262144);
  tcast<float><<<dim3(8,8,1),        tblk, 0, stream>>>(Wg,  WgT,  256, 256, 0, 0);

  for (int l=0; l<DEPTH_; l++){
    // xT[b] = bf16(x[b])^T
    tcast<float><<<dim3(8,32,B_), tblk, 0, stream>>>(xf, xT, 256, 1024, 262144, 262144);
    // tmp1 = G @ x   (z = batch)
    gemm(stream, Gb, xT, tmp1b, 1, 0, 1024, 256, 1024, 1024, 1024, 256, B_, 0,
         1048576,0, 262144,0, 262144,0, 1.f, nullptr, nullptr, nullptr);
    // tmp2 = tmp1 @ Wg
    gemm(stream, tmp1b, WgT, tmp2b, 1, 0, 4096, 256, 256, 256, 256, 256, 1, 0,
         0,0,0,0,0,0, 1.f, nullptr, nullptr, nullptr);
    // x_ma = relu(LN(tmp2))
    ln_kernel<u16><<<dim3(B_*N_), b256, 0, stream>>>(tmp2b, xmab, lng_g, lng_b, 1);
    // xn = LN(x)
    ln_kernel<float><<<dim3(B_*N_), b256, 0, stream>>>(xf, xnb, ln1_g + l*DIM_, ln1_b + l*DIM_, 0);
    // kv = xn @ Wkv[l]
    gemm(stream, xnb, WkvT + (long long)l*131072, kvb, 1, 0, 4096, 512, 256, 256, 256, 512, 1, 0,
         0,0,0,0,0,0, 1.f, nullptr, nullptr, nullptr);
    // vt[b] = V^T
    tcast<u16><<<dim3(8,32,B_), tblk, 0, stream>>>(kvb + 256, vt, 512, 1024, 524288, 262144);
    // q = x_ma @ Wq[l]
    gemm(stream, xmab, WqT + (long long)l*65536, qb, 1, 0, 4096, 256, 256, 256, 256, 256, 1, 0,
         0,0,0,0,0,0, 1.f, nullptr, nullptr, nullptr);
    // S = q k^T * scale + bsum   (z = b*4+h)
    gemm(stream, qb, kvb, S, 1, 0, 1024, 1024, 64, 256, 512, 1024, B_*HEADS_, 2,
         262144,64, 524288,64, 4194304,1048576, 0.0625f, nullptr, bsum, nullptr);
    // P = softmax(S) in place
    softmax_rows<<<dim3(B_*HEADS_*N_), b256, 0, stream>>>(S);
    // ao = P @ V    (z = b*4+h)
    gemm(stream, S, vt, aob, 1, 0, 1024, 64, 1024, 1024, 1024, 256, B_*HEADS_, 2,
         4194304,1048576, 262144,65536, 262144,64, 1.f, nullptr, nullptr, nullptr);
    // x = x + ao @ Wo[l] + bo[l]
    gemm(stream, aob, WoT + (long long)l*65536, xf, 0, 0, 4096, 256, 256, 256, 256, 256, 1, 0,
         0,0,0,0,0,0, 1.f, bo + l*DIM_, nullptr, xf);
    // xn2 = LN(x)
    ln_kernel<float><<<dim3(B_*N_), b256, 0, stream>>>(xf, xnb, ln2_g + l*DIM_, ln2_b + l*DIM_, 0);
    // h1 = gelu(xn2 @ W1[l] + b1[l])
    gemm(stream, xnb, W1T + (long long)l*262144, h1b, 1, 1, 4096, 1024, 256, 256, 256, 1024, 1, 0,
         0,0,0,0,0,0, 1.f, b1 + l*MLP_, nullptr, nullptr);
    // x = x + h1 @ W2[l] + b2[l]  (last layer -> d_out)
    float* Cdst = (l == DEPTH_-1) ? (float*)d_out : xf;
    gemm(stream, h1b, W2T + (long long)l*262144, Cdst, 0, 0, 4096, 256, 1024, 1024, 1024, 256, 1, 0,
         0,0,0,0,0,0, 1.f, b2 + l*DIM_, nullptr, xf);
  }
}